// Round 2
// baseline (63.877 us; speedup 1.0000x reference)
//
#include <hip/hip_runtime.h>

constexpr int   SCELLS       = 49;          // S*S
constexpr int   BATCH        = 16384;
constexpr int   CELLS        = BATCH * SCELLS;   // 802816
constexpr int   F            = 30;          // 5*B + C
constexpr float LAMBDA_COORD = 5.0f;
constexpr float LAMBDA_NOOBJ = 0.5f;
constexpr float EPS_WH       = 1e-6f;
constexpr float EPS_IOU      = 1e-6f;

__device__ __forceinline__ float iou_yolo(const float b0, const float b1,
                                          const float b2, const float b3,
                                          const float c0, const float c1,
                                          const float c2, const float c3) {
    float b1x1 = b0 - b2 * 0.5f;
    float b1y1 = b1 - b3 * 0.5f;
    float b1x2 = b0 + b2 * 0.5f;
    float b1y2 = b1 + b3 * 0.5f;
    float b2x1 = c0 - c2 * 0.5f;
    float b2y1 = c1 - c3 * 0.5f;
    float b2x2 = c0 + c2 * 0.5f;
    float b2y2 = c1 + c3 * 0.5f;
    float iw = fmaxf(fminf(b1x2, b2x2) - fmaxf(b1x1, b2x1), 0.0f);
    float ih = fmaxf(fminf(b1y2, b2y2) - fmaxf(b1y1, b2y1), 0.0f);
    float inter = iw * ih;
    float a1 = fabsf((b1x2 - b1x1) * (b1y2 - b1y1));
    float a2 = fabsf((b2x2 - b2x1) * (b2y2 - b2y1));
    return inter / (a1 + a2 - inter + EPS_IOU);
}

__global__ void __launch_bounds__(256)
yolo_loss_kernel(const float* __restrict__ yt_g,
                 const float* __restrict__ yp_g,
                 float* __restrict__ out) {
    const int cell = blockIdx.x * blockDim.x + threadIdx.x;

    float loss = 0.0f;
    if (cell < CELLS) {
        // Cell base = cell*30 floats = cell*120 bytes -> 8B aligned: use float2.
        const float2* t2 = reinterpret_cast<const float2*>(yt_g + (size_t)cell * F);
        const float2* p2 = reinterpret_cast<const float2*>(yp_g + (size_t)cell * F);
        float t[F], p[F];
#pragma unroll
        for (int k = 0; k < F / 2; ++k) {
            float2 v = t2[k]; t[2 * k] = v.x; t[2 * k + 1] = v.y;
            float2 w = p2[k]; p[2 * k] = w.x; p[2 * k + 1] = w.y;
        }

        const float objf   = (t[4] == 1.0f) ? 1.0f : 0.0f;
        const float noobjf = 1.0f - objf;

        const float iou1 = iou_yolo(t[0], t[1], t[2], t[3], p[0], p[1], p[2], p[3]);
        const float iou2 = iou_yolo(t[0], t[1], t[2], t[3], p[5], p[6], p[7], p[8]);
        const bool  best1 = iou1 > iou2;

        // Constant-index selects only (keep arrays in registers).
        const float bh0 = best1 ? p[0] : p[5];
        const float bh1 = best1 ? p[1] : p[6];
        const float bh2 = best1 ? p[2] : p[7];
        const float bh3 = best1 ? p[3] : p[8];
        const float confhat = best1 ? p[4] : p[9];

        // xy
        const float dx = t[0] - bh0;
        const float dy = t[1] - bh1;
        const float xy = dx * dx + dy * dy;
        // wh
        const float wt = sqrtf(t[2]) - sqrtf(fabsf(bh2 + EPS_WH));
        const float ht = sqrtf(t[3]) - sqrtf(fabsf(bh3 + EPS_WH));
        const float wh = wt * wt + ht * ht;
        // conf
        const float dc = t[4] - confhat;
        // class
        float cls = 0.0f;
#pragma unroll
        for (int c = 10; c < F; ++c) {
            const float d = t[c] - p[c];
            cls += d * d;
        }
        // noobj: reference slices yp[..., 4::5] -> channels 4,9,14,19,24,29
        float noobj = 0.0f;
#pragma unroll
        for (int c = 4; c < F; c += 5) {
            const float d = t[4] - p[c];
            noobj += d * d;
        }

        loss = objf * (LAMBDA_COORD * (xy + wh) + dc * dc + cls)
             + noobjf * (LAMBDA_NOOBJ * noobj);
    }

    // Wave64 shuffle reduction.
#pragma unroll
    for (int off = 32; off > 0; off >>= 1) loss += __shfl_down(loss, off);

    __shared__ float wsum[4];
    const int lane = threadIdx.x & 63;
    const int wid  = threadIdx.x >> 6;
    if (lane == 0) wsum[wid] = loss;
    __syncthreads();
    if (threadIdx.x == 0) {
        const float s = wsum[0] + wsum[1] + wsum[2] + wsum[3];
        atomicAdd(out, s * (1.0f / (float)BATCH));
    }
}

extern "C" void kernel_launch(void* const* d_in, const int* in_sizes, int n_in,
                              void* d_out, int out_size, void* d_ws, size_t ws_size,
                              hipStream_t stream) {
    const float* y_trues = (const float*)d_in[0];
    const float* y_preds = (const float*)d_in[1];
    float* out = (float*)d_out;

    // Harness poisons d_out once and never re-poisons between replays:
    // zero it ourselves every call (memset node is graph-capture safe).
    hipMemsetAsync(out, 0, sizeof(float) * (size_t)out_size, stream);

    const int block = 256;
    const int grid  = (CELLS + block - 1) / block;   // 3136
    yolo_loss_kernel<<<grid, block, 0, stream>>>(y_trues, y_preds, out);
}

// Round 3
// 61.441 us; speedup vs baseline: 1.0396x; 1.0396x over previous
//
#include <hip/hip_runtime.h>

constexpr int   SCELLS       = 49;               // S*S
constexpr int   BATCH        = 16384;
constexpr int   CELLS        = BATCH * SCELLS;   // 802816 = 3136 * 256 exactly
constexpr int   F            = 30;               // 5*B + C
constexpr int   CPB          = 256;              // cells per block
constexpr int   FLTS         = CPB * F;          // 7680 floats per input per block
constexpr int   VEC4         = FLTS / 4;         // 1920 float4
constexpr float LAMBDA_COORD = 5.0f;
constexpr float LAMBDA_NOOBJ = 0.5f;
constexpr float EPS_WH       = 1e-6f;
constexpr float EPS_IOU      = 1e-6f;

__device__ __forceinline__ float iou_yolo(const float b0, const float b1,
                                          const float b2, const float b3,
                                          const float c0, const float c1,
                                          const float c2, const float c3) {
    float b1x1 = b0 - b2 * 0.5f;
    float b1y1 = b1 - b3 * 0.5f;
    float b1x2 = b0 + b2 * 0.5f;
    float b1y2 = b1 + b3 * 0.5f;
    float b2x1 = c0 - c2 * 0.5f;
    float b2y1 = c1 - c3 * 0.5f;
    float b2x2 = c0 + c2 * 0.5f;
    float b2y2 = c1 + c3 * 0.5f;
    float iw = fmaxf(fminf(b1x2, b2x2) - fmaxf(b1x1, b2x1), 0.0f);
    float ih = fmaxf(fminf(b1y2, b2y2) - fmaxf(b1y1, b2y1), 0.0f);
    float inter = iw * ih;
    float a1 = fabsf((b1x2 - b1x1) * (b1y2 - b1y1));
    float a2 = fabsf((b2x2 - b2x1) * (b2y2 - b2y1));
    return inter / (a1 + a2 - inter + EPS_IOU);
}

__global__ void __launch_bounds__(256)
yolo_loss_kernel(const float* __restrict__ yt_g,
                 const float* __restrict__ yp_g,
                 float* __restrict__ out) {
    __shared__ float lt[FLTS];
    __shared__ float lp[FLTS];

    // ---- Coalesced staging: lane-contiguous float4 (16 lines/wave-instr) ----
    const size_t base_f = (size_t)blockIdx.x * FLTS;
    const float4* tg = reinterpret_cast<const float4*>(yt_g + base_f);
    const float4* pg = reinterpret_cast<const float4*>(yp_g + base_f);
    float4* lt4 = reinterpret_cast<float4*>(lt);
    float4* lp4 = reinterpret_cast<float4*>(lp);
#pragma unroll
    for (int k = 0; k < 7; ++k) {
        const int idx = threadIdx.x + k * 256;
        lt4[idx] = tg[idx];
        lp4[idx] = pg[idx];
    }
    {
        const int idx = threadIdx.x + 7 * 256;   // 1792..2047, keep < 1920
        if (idx < VEC4) {
            lt4[idx] = tg[idx];
            lp4[idx] = pg[idx];
        }
    }
    __syncthreads();

    // ---- Per-cell compute from LDS (stride-30 float2 reads, ~4-way conflict) ----
    const float2* t2 = reinterpret_cast<const float2*>(lt + threadIdx.x * F);
    const float2* p2 = reinterpret_cast<const float2*>(lp + threadIdx.x * F);
    float t[F], p[F];
#pragma unroll
    for (int k = 0; k < F / 2; ++k) {
        float2 v = t2[k]; t[2 * k] = v.x; t[2 * k + 1] = v.y;
        float2 w = p2[k]; p[2 * k] = w.x; p[2 * k + 1] = w.y;
    }

    const float objf   = (t[4] == 1.0f) ? 1.0f : 0.0f;
    const float noobjf = 1.0f - objf;

    const float iou1 = iou_yolo(t[0], t[1], t[2], t[3], p[0], p[1], p[2], p[3]);
    const float iou2 = iou_yolo(t[0], t[1], t[2], t[3], p[5], p[6], p[7], p[8]);
    const bool  best1 = iou1 > iou2;

    // Constant-index selects only (keep arrays in registers).
    const float bh0 = best1 ? p[0] : p[5];
    const float bh1 = best1 ? p[1] : p[6];
    const float bh2 = best1 ? p[2] : p[7];
    const float bh3 = best1 ? p[3] : p[8];
    const float confhat = best1 ? p[4] : p[9];

    // xy
    const float dx = t[0] - bh0;
    const float dy = t[1] - bh1;
    const float xy = dx * dx + dy * dy;
    // wh
    const float wt = sqrtf(t[2]) - sqrtf(fabsf(bh2 + EPS_WH));
    const float ht = sqrtf(t[3]) - sqrtf(fabsf(bh3 + EPS_WH));
    const float wh = wt * wt + ht * ht;
    // conf
    const float dc = t[4] - confhat;
    // class
    float cls = 0.0f;
#pragma unroll
    for (int c = 10; c < F; ++c) {
        const float d = t[c] - p[c];
        cls += d * d;
    }
    // noobj: reference slices yp[..., 4::5] -> channels 4,9,14,19,24,29
    float noobj = 0.0f;
#pragma unroll
    for (int c = 4; c < F; c += 5) {
        const float d = t[4] - p[c];
        noobj += d * d;
    }

    float loss = objf * (LAMBDA_COORD * (xy + wh) + dc * dc + cls)
               + noobjf * (LAMBDA_NOOBJ * noobj);

    // Wave64 shuffle reduction.
#pragma unroll
    for (int off = 32; off > 0; off >>= 1) loss += __shfl_down(loss, off);

    __shared__ float wsum[4];
    const int lane = threadIdx.x & 63;
    const int wid  = threadIdx.x >> 6;
    if (lane == 0) wsum[wid] = loss;
    __syncthreads();
    if (threadIdx.x == 0) {
        const float s = wsum[0] + wsum[1] + wsum[2] + wsum[3];
        atomicAdd(out, s * (1.0f / (float)BATCH));
    }
}

extern "C" void kernel_launch(void* const* d_in, const int* in_sizes, int n_in,
                              void* d_out, int out_size, void* d_ws, size_t ws_size,
                              hipStream_t stream) {
    const float* y_trues = (const float*)d_in[0];
    const float* y_preds = (const float*)d_in[1];
    float* out = (float*)d_out;

    // Harness poisons d_out once and never re-poisons between replays:
    // zero it ourselves every call (memset node is graph-capture safe).
    hipMemsetAsync(out, 0, sizeof(float) * (size_t)out_size, stream);

    const int block = 256;
    const int grid  = CELLS / CPB;   // 3136, exact
    yolo_loss_kernel<<<grid, block, 0, stream>>>(y_trues, y_preds, out);
}

// Round 5
// 55.616 us; speedup vs baseline: 1.1485x; 1.1047x over previous
//
#include <hip/hip_runtime.h>

constexpr int   SCELLS       = 49;
constexpr int   BATCH        = 16384;
constexpr int   CELLS        = BATCH * SCELLS;   // 802816 = 6272 * 128
constexpr int   F            = 30;
constexpr int   CPB          = 128;              // cells per block
constexpr int   FLTS         = CPB * F;          // 3840 floats per input per block
constexpr int   BYTES_PER_IN = FLTS * 4;         // 15360 B
constexpr int   CHUNK        = 64 * 16;          // 1024 B per wave-instruction (16 B/lane)
constexpr int   NCHUNK       = BYTES_PER_IN / CHUNK;  // 15 chunks per input
constexpr int   NSLOT        = 64;               // atomic shards in d_ws
constexpr float LAMBDA_COORD = 5.0f;
constexpr float LAMBDA_NOOBJ = 0.5f;
constexpr float EPS_WH       = 1e-6f;
constexpr float EPS_IOU      = 1e-6f;

__device__ __forceinline__ void load_lds16(const void* g, void* l) {
    __builtin_amdgcn_global_load_lds(
        (const __attribute__((address_space(1))) unsigned int*)g,
        (__attribute__((address_space(3))) unsigned int*)l,
        16, 0, 0);   // 16 B/lane — the HW-verified width (m97)
}

__device__ __forceinline__ float iou_yolo(const float b0, const float b1,
                                          const float b2, const float b3,
                                          const float c0, const float c1,
                                          const float c2, const float c3) {
    float b1x1 = b0 - b2 * 0.5f;
    float b1y1 = b1 - b3 * 0.5f;
    float b1x2 = b0 + b2 * 0.5f;
    float b1y2 = b1 + b3 * 0.5f;
    float b2x1 = c0 - c2 * 0.5f;
    float b2y1 = c1 - c3 * 0.5f;
    float b2x2 = c0 + c2 * 0.5f;
    float b2y2 = c1 + c3 * 0.5f;
    float iw = fmaxf(fminf(b1x2, b2x2) - fmaxf(b1x1, b2x1), 0.0f);
    float ih = fmaxf(fminf(b1y2, b2y2) - fmaxf(b1y1, b2y1), 0.0f);
    float inter = iw * ih;
    float a1 = fabsf((b1x2 - b1x1) * (b1y2 - b1y1));
    float a2 = fabsf((b2x2 - b2x1) * (b2y2 - b2y1));
    return inter / (a1 + a2 - inter + EPS_IOU);
}

__global__ void __launch_bounds__(128)
yolo_loss_kernel(const float* __restrict__ yt_g,
                 const float* __restrict__ yp_g,
                 float* __restrict__ ws) {
    __shared__ float lt[FLTS];
    __shared__ float lp[FLTS];

    const int tid  = threadIdx.x;
    const int lane = tid & 63;
    const int wid  = tid >> 6;

    // ---- DMA staging: wave 0 -> lt, wave 1 -> lp; 15 x 1024 B chunks each ----
    const size_t blk_byte = (size_t)blockIdx.x * BYTES_PER_IN;
    const char* src = (wid == 0) ? (const char*)yt_g + blk_byte
                                 : (const char*)yp_g + blk_byte;
    char* dst = (wid == 0) ? (char*)lt : (char*)lp;
#pragma unroll
    for (int j = 0; j < NCHUNK; ++j) {
        const int off = j * CHUNK;                  // wave-uniform LDS offset
        load_lds16(src + off + lane * 16, dst + off);
    }
    asm volatile("s_waitcnt vmcnt(0)" ::: "memory");
    __syncthreads();

    // ---- Per-cell compute from LDS (stride-30 float2 reads, 4-way conflict, tiny) ----
    const float2* t2 = reinterpret_cast<const float2*>(lt + tid * F);
    const float2* p2 = reinterpret_cast<const float2*>(lp + tid * F);
    float t[F], p[F];
#pragma unroll
    for (int k = 0; k < F / 2; ++k) {
        float2 v = t2[k]; t[2 * k] = v.x; t[2 * k + 1] = v.y;
        float2 w = p2[k]; p[2 * k] = w.x; p[2 * k + 1] = w.y;
    }

    const float objf   = (t[4] == 1.0f) ? 1.0f : 0.0f;
    const float noobjf = 1.0f - objf;

    const float iou1 = iou_yolo(t[0], t[1], t[2], t[3], p[0], p[1], p[2], p[3]);
    const float iou2 = iou_yolo(t[0], t[1], t[2], t[3], p[5], p[6], p[7], p[8]);
    const bool  best1 = iou1 > iou2;

    const float bh0 = best1 ? p[0] : p[5];
    const float bh1 = best1 ? p[1] : p[6];
    const float bh2 = best1 ? p[2] : p[7];
    const float bh3 = best1 ? p[3] : p[8];
    const float confhat = best1 ? p[4] : p[9];

    const float dx = t[0] - bh0;
    const float dy = t[1] - bh1;
    const float xy = dx * dx + dy * dy;

    const float wt = sqrtf(t[2]) - sqrtf(fabsf(bh2 + EPS_WH));
    const float ht = sqrtf(t[3]) - sqrtf(fabsf(bh3 + EPS_WH));
    const float wh = wt * wt + ht * ht;

    const float dc = t[4] - confhat;

    float cls = 0.0f;
#pragma unroll
    for (int c = 10; c < F; ++c) {
        const float d = t[c] - p[c];
        cls += d * d;
    }
    // noobj: reference slices yp[..., 4::5] -> channels 4,9,14,19,24,29
    float noobj = 0.0f;
#pragma unroll
    for (int c = 4; c < F; c += 5) {
        const float d = t[4] - p[c];
        noobj += d * d;
    }

    float loss = objf * (LAMBDA_COORD * (xy + wh) + dc * dc + cls)
               + noobjf * (LAMBDA_NOOBJ * noobj);

    // Wave64 shuffle reduction.
#pragma unroll
    for (int off = 32; off > 0; off >>= 1) loss += __shfl_down(loss, off);

    __shared__ float wsum[2];
    if (lane == 0) wsum[wid] = loss;
    __syncthreads();
    if (tid == 0) {
        atomicAdd(ws + (blockIdx.x & (NSLOT - 1)), wsum[0] + wsum[1]);
    }
}

__global__ void __launch_bounds__(64)
yolo_finalize_kernel(const float* __restrict__ ws, float* __restrict__ out) {
    float s = ws[threadIdx.x];
#pragma unroll
    for (int off = 32; off > 0; off >>= 1) s += __shfl_down(s, off);
    if (threadIdx.x == 0) out[0] = s * (1.0f / (float)BATCH);
}

extern "C" void kernel_launch(void* const* d_in, const int* in_sizes, int n_in,
                              void* d_out, int out_size, void* d_ws, size_t ws_size,
                              hipStream_t stream) {
    const float* y_trues = (const float*)d_in[0];
    const float* y_preds = (const float*)d_in[1];
    float* out = (float*)d_out;
    float* ws  = (float*)d_ws;

    // Zero the atomic shards every call (harness poisons ws once, never re-poisons).
    hipMemsetAsync(ws, 0, sizeof(float) * NSLOT, stream);

    const int grid = CELLS / CPB;   // 6272, exact
    yolo_loss_kernel<<<grid, 128, 0, stream>>>(y_trues, y_preds, ws);
    yolo_finalize_kernel<<<1, 64, 0, stream>>>(ws, out);
}

// Round 6
// 41.606 us; speedup vs baseline: 1.5353x; 1.3367x over previous
//
#include <hip/hip_runtime.h>

constexpr int   BATCH        = 16384;
constexpr int   CELLS        = 802816;            // BATCH * 49
constexpr int   F            = 30;
constexpr int   CPB          = 128;               // cells per tile
constexpr int   NTILES       = CELLS / CPB;       // 6272 exact
constexpr int   FLTS         = CPB * F;           // 3840 floats / input / tile
constexpr int   TILE_B       = FLTS * 4;          // 15360 B
constexpr int   CHUNK        = 1024;              // 64 lanes x 16 B per DMA instr
constexpr int   NCHUNK       = TILE_B / CHUNK;    // 15
constexpr int   GRID         = 512;               // 2 persistent blocks per CU
constexpr float LAMBDA_COORD = 5.0f;
constexpr float LAMBDA_NOOBJ = 0.5f;
constexpr float EPS_WH       = 1e-6f;
constexpr float EPS_IOU      = 1e-6f;

__device__ __forceinline__ void load_lds16(const void* g, void* l) {
    __builtin_amdgcn_global_load_lds(
        (const __attribute__((address_space(1))) unsigned int*)g,
        (__attribute__((address_space(3))) unsigned int*)l,
        16, 0, 0);   // 16 B/lane — HW-verified width
}

__device__ __forceinline__ void block_barrier() {
    asm volatile("" ::: "memory");
    __builtin_amdgcn_s_barrier();
    asm volatile("" ::: "memory");
}

__device__ __forceinline__ float iou_yolo(const float b0, const float b1,
                                          const float b2, const float b3,
                                          const float c0, const float c1,
                                          const float c2, const float c3) {
    float b1x1 = b0 - b2 * 0.5f;
    float b1y1 = b1 - b3 * 0.5f;
    float b1x2 = b0 + b2 * 0.5f;
    float b1y2 = b1 + b3 * 0.5f;
    float b2x1 = c0 - c2 * 0.5f;
    float b2y1 = c1 - c3 * 0.5f;
    float b2x2 = c0 + c2 * 0.5f;
    float b2y2 = c1 + c3 * 0.5f;
    float iw = fmaxf(fminf(b1x2, b2x2) - fmaxf(b1x1, b2x1), 0.0f);
    float ih = fmaxf(fminf(b1y2, b2y2) - fmaxf(b1y1, b2y1), 0.0f);
    float inter = iw * ih;
    float a1 = fabsf((b1x2 - b1x1) * (b1y2 - b1y1));
    float a2 = fabsf((b2x2 - b2x1) * (b2y2 - b2y1));
    return inter / (a1 + a2 - inter + EPS_IOU);
}

__global__ void __launch_bounds__(128)
yolo_loss_kernel(const float* __restrict__ yt_g,
                 const float* __restrict__ yp_g,
                 float* __restrict__ out) {
    // [buffer][input(t/p)][tile floats] — double-buffered, 61440 B total.
    __shared__ __align__(16) float lbuf[2][2][FLTS];

    const int tid  = threadIdx.x;
    const int lane = tid & 63;
    const int wid  = tid >> 6;           // wave 0 stages y_trues, wave 1 stages y_preds

    const char* src_base = (wid == 0) ? (const char*)yt_g : (const char*)yp_g;

    // ---- Prologue: stage first tile into buffer 0 (15 DMA chunks per wave) ----
    int tile = blockIdx.x;
    {
        const char* s = src_base + (size_t)tile * TILE_B + lane * 16;
        char* d = (char*)lbuf[0][wid];
#pragma unroll
        for (int j = 0; j < NCHUNK; ++j)
            load_lds16(s + j * CHUNK, d + j * CHUNK);
    }

    float acc = 0.0f;
    int buf = 0;

    for (; tile < NTILES; tile += GRID) {
        const int next = tile + GRID;
        if (next < NTILES) {             // block-uniform branch
            // Issue next tile's DMA into the other buffer — no wait yet.
            const char* s = src_base + (size_t)next * TILE_B + lane * 16;
            char* d = (char*)lbuf[buf ^ 1][wid];
#pragma unroll
            for (int j = 0; j < NCHUNK; ++j)
                load_lds16(s + j * CHUNK, d + j * CHUNK);
            // Wait only for the CURRENT tile's 15 chunks (15 newer stay in flight).
            asm volatile("s_waitcnt vmcnt(15)" ::: "memory");
        } else {
            asm volatile("s_waitcnt vmcnt(0)" ::: "memory");
        }
        block_barrier();                 // raw s_barrier: no vmcnt(0) drain

        // ---- Compute current tile from LDS ----
        const float2* t2 = reinterpret_cast<const float2*>(&lbuf[buf][0][tid * F]);
        const float2* p2 = reinterpret_cast<const float2*>(&lbuf[buf][1][tid * F]);
        float t[F], p[F];
        {   // t: need channels 0..4 and 10..29 (skip dead 5..9 -> 13 reads)
            float2 v;
            v = t2[0]; t[0] = v.x; t[1] = v.y;
            v = t2[1]; t[2] = v.x; t[3] = v.y;
            v = t2[2]; t[4] = v.x;
#pragma unroll
            for (int k = 5; k < 15; ++k) { v = t2[k]; t[2 * k] = v.x; t[2 * k + 1] = v.y; }
        }
#pragma unroll
        for (int k = 0; k < 15; ++k) { float2 w = p2[k]; p[2 * k] = w.x; p[2 * k + 1] = w.y; }

        const float objf   = (t[4] == 1.0f) ? 1.0f : 0.0f;
        const float noobjf = 1.0f - objf;

        const float iou1 = iou_yolo(t[0], t[1], t[2], t[3], p[0], p[1], p[2], p[3]);
        const float iou2 = iou_yolo(t[0], t[1], t[2], t[3], p[5], p[6], p[7], p[8]);
        const bool  best1 = iou1 > iou2;

        const float bh0 = best1 ? p[0] : p[5];
        const float bh1 = best1 ? p[1] : p[6];
        const float bh2 = best1 ? p[2] : p[7];
        const float bh3 = best1 ? p[3] : p[8];
        const float confhat = best1 ? p[4] : p[9];

        const float dx = t[0] - bh0;
        const float dy = t[1] - bh1;
        const float xy = dx * dx + dy * dy;

        const float wt = sqrtf(t[2]) - sqrtf(fabsf(bh2 + EPS_WH));
        const float ht = sqrtf(t[3]) - sqrtf(fabsf(bh3 + EPS_WH));
        const float wh = wt * wt + ht * ht;

        const float dc = t[4] - confhat;

        float cls = 0.0f;
#pragma unroll
        for (int c = 10; c < F; ++c) {
            const float d = t[c] - p[c];
            cls += d * d;
        }
        // noobj: reference slices yp[..., 4::5] -> channels 4,9,14,19,24,29
        float noobj = 0.0f;
#pragma unroll
        for (int c = 4; c < F; c += 5) {
            const float d = t[4] - p[c];
            noobj += d * d;
        }

        acc += objf * (LAMBDA_COORD * (xy + wh) + dc * dc + cls)
             + noobjf * (LAMBDA_NOOBJ * noobj);

        block_barrier();                 // all waves done reading buf before it's re-staged
        buf ^= 1;
    }

    // ---- Final reduction: wave shuffle -> LDS -> one atomic per block ----
#pragma unroll
    for (int off = 32; off > 0; off >>= 1) acc += __shfl_down(acc, off);

    __shared__ float wsum[2];
    if (lane == 0) wsum[wid] = acc;
    __syncthreads();
    if (tid == 0) atomicAdd(out, (wsum[0] + wsum[1]) * (1.0f / (float)BATCH));
}

extern "C" void kernel_launch(void* const* d_in, const int* in_sizes, int n_in,
                              void* d_out, int out_size, void* d_ws, size_t ws_size,
                              hipStream_t stream) {
    const float* y_trues = (const float*)d_in[0];
    const float* y_preds = (const float*)d_in[1];
    float* out = (float*)d_out;

    // Harness poisons d_out once, never re-poisons between replays: zero it every call.
    hipMemsetAsync(out, 0, sizeof(float) * (size_t)out_size, stream);

    yolo_loss_kernel<<<GRID, 128, 0, stream>>>(y_trues, y_preds, out);
}